// Round 11
// baseline (390.958 us; speedup 1.0000x reference)
//
#include <hip/hip_runtime.h>
#include <math.h>

// Problem constants
#define TT 8
#define NTOK 32768
#define DD 128
#define LCOMP 8
#define GSZ 8192
#define CDIM 64
#define EDIM 128
#define NPART 8

#define BATCH 16                       // tokens per wave-batch
#define BPW 8                          // batches per wave
#define WAVES 4
#define TOKBLK (WAVES*BPW*BATCH)       // 512 tokens per block
#define NBLK (TT*NTOK/TOKBLK)          // 512 blocks = 2/CU, all resident

// workspace byte offsets
#define O_CZERO 0                            // 64 f32
#define O_W2BT  256                          // 64*128 bf16 [k][j] linear
#define O_W1BT  (256 + EDIM*CDIM*2)          // 128*128 bf16 [j][d] linear
#define O_CSUMP (O_W1BT + DD*EDIM*2)         // 8*64*64 f32 partials

typedef __attribute__((ext_vector_type(8))) short bf16x8;
typedef __attribute__((ext_vector_type(4))) float f32x4;

__device__ __forceinline__ ushort f2bf(float f) {
    union { float f; uint u; } c; c.f = f;
    uint u = c.u;
    return (ushort)((u + 0x7FFFu + ((u >> 16) & 1u)) >> 16);
}

// gelu via Abramowitz-Stegun 7.1.26 erf (|eps| <= 1.5e-7)
__device__ __forceinline__ float gelu_f(float a) {
    float x = a * 0.70710678118654752f;
    float ax = fabsf(x);
    float t = 1.0f / (1.0f + 0.3275911f * ax);
    float p = t * (0.254829592f + t * (-0.284496736f + t * (1.421413741f +
              t * (-1.453152027f + t * 1.061405429f))));
    float e = __expf(-x * x);
    float er = copysignf(1.0f - p * e, x);
    return 0.5f * a * (1.0f + er);
}

// ---------------- prep: bf16 transposed weights (linear), czero, zero csum_p
__global__ void prep_kernel(const float* __restrict__ w1, const float* __restrict__ b1,
                            const float* __restrict__ w2,
                            ushort* __restrict__ w1bt, ushort* __restrict__ w2bt,
                            float* __restrict__ czero, float* __restrict__ csum_p) {
    int gid = blockIdx.x * 256 + threadIdx.x;
    if (gid < DD * EDIM) {                 // w1bt[j][d] linear (register A-frags now)
        int j = gid >> 7, d = gid & 127;
        w1bt[j * 128 + d] = f2bf(w1[d * EDIM + j]);
    }
    if (gid < EDIM * CDIM) {               // w2bt[k][j] linear
        int k = gid >> 7, jj = gid & 127;
        w2bt[k * 128 + jj] = f2bf(w2[jj * CDIM + k]);
    }
    if (gid < CDIM) {
        float a2 = 0.f;
        for (int dd = 0; dd < EDIM; ++dd)
            a2 += gelu_f(b1[dd]) * w2[dd * CDIM + gid];
        czero[gid] = a2;
    }
#pragma unroll
    for (int i = 0; i < 2; ++i)            // zero 8*64*64 partial sums
        csum_p[gid + i * 16384] = 0.f;
}

// ---------------- main: barrier-free per-wave LN+MLP, swapped-operand MFMA --
// Swapped GEMMs: D1[j][tok]=w1t·xn, D2[k][tok]=w2t·h. B-frag (col=tok,
// k=(l>>4)*8+e) == the strided x load, so xn feeds MFMA from registers.
// Weights in registers; h transposed through a 4KB PER-WAVE LDS patch
// (same-wave ds ops, lgkmcnt-ordered, NO __syncthreads in the loop).
__global__ __launch_bounds__(256, 2)
void main_kernel(const float* __restrict__ x,
                 const float* __restrict__ ln1w, const float* __restrict__ ln1b,
                 const float* __restrict__ b1g,
                 const ushort* __restrict__ w1bt, const ushort* __restrict__ w2bt,
                 const float* __restrict__ czero,
                 const int* __restrict__ node_idx,
                 float* __restrict__ csum_p) {
    __shared__ ushort s_h[WAVES * 2048];   // 4KB per wave: h[16tok][128j] bf16 swizzled
    __shared__ float  s_acc[LCOMP * 65];   // stride-65 pad: bank = (lg+k)%32

    const int tid = threadIdx.x;
    const int w   = tid >> 6;
    const int ln  = tid & 63;
    const int cs  = ln >> 4;               // k-slice group (4 lanes per token)
    const int tk  = ln & 15;               // token-in-batch = MFMA col
    const int bid = blockIdx.x;

    for (int idx = tid; idx < LCOMP * 65; idx += 256) s_acc[idx] = 0.f;

    // ---- persistent register state (whole wave lifetime) ----
    bf16x8 w1f[8][4];                      // A-frags of w1t: 64 VGPR
#pragma unroll
    for (int jt = 0; jt < 8; ++jt)
#pragma unroll
        for (int ks = 0; ks < 4; ++ks)
            w1f[jt][ks] = *(const bf16x8*)(w1bt + (jt*16 + tk)*128 + ks*32 + cs*8);
    bf16x8 w2f[4][4];                      // A-frags of w2t: 32 VGPR
#pragma unroll
    for (int kt = 0; kt < 4; ++kt)
#pragma unroll
        for (int ks = 0; ks < 4; ++ks)
            w2f[kt][ks] = *(const bf16x8*)(w2bt + (kt*16 + tk)*128 + ks*32 + cs*8);
    f32x4 b1v[8];                          // GEMM1 acc init = bias
#pragma unroll
    for (int jt = 0; jt < 8; ++jt)
        b1v[jt] = *(const f32x4*)(b1g + jt*16 + cs*4);
    f32x4 czv[4];                          // GEMM2 acc init = -czero
#pragma unroll
    for (int kt = 0; kt < 4; ++kt)
        czv[kt] = -*(const f32x4*)(czero + kt*16 + cs*4);

    __syncthreads();                       // barrier 1: s_acc zeroed

    const size_t wbase = (size_t)bid * TOKBLK + w * (BPW * BATCH);
    char* hbase = (char*)s_h + w * 4096;

    // preload batch 0: lane holds x[tok=tk][d in {m*32+cs*8 .. +8}] (B-frag layout)
    float v[32];
    {
        const float* xp = x + (wbase + tk) * (size_t)DD;
#pragma unroll
        for (int m = 0; m < 4; ++m) {
            *(float4*)(v + m*8)     = *(const float4*)(xp + m*32 + cs*8);
            *(float4*)(v + m*8 + 4) = *(const float4*)(xp + m*32 + cs*8 + 4);
        }
    }

    for (int b = 0; b < BPW; ++b) {
        const size_t tb = wbase + (size_t)b * BATCH;
        const int lg = node_idx[tb + tk] >> 13;   // token's group

        // ---- LayerNorm (4 lanes/token via xor 16,32) ----
        float s = 0.f, q = 0.f;
#pragma unroll
        for (int i = 0; i < 32; ++i) { s += v[i]; q += v[i]*v[i]; }
        s += __shfl_xor(s, 16, 64); q += __shfl_xor(q, 16, 64);
        s += __shfl_xor(s, 32, 64); q += __shfl_xor(q, 32, 64);
        float mean = s * (1.f/128.f);
        float var  = q * (1.f/128.f) - mean*mean;
        float rs   = rsqrtf(var + 1e-5f);

        bf16x8 xnf[4];                     // = GEMM1 B-frags, built in-register
#pragma unroll
        for (int m = 0; m < 4; ++m) {
            const float* lwp = ln1w + m*32 + cs*8;
            const float* lbp = ln1b + m*32 + cs*8;
            float4 lw0 = *(const float4*)(lwp),   lw1 = *(const float4*)(lwp + 4);
            float4 lb0 = *(const float4*)(lbp),   lb1 = *(const float4*)(lbp + 4);
            float g0 = (v[m*8+0]-mean)*rs*lw0.x + lb0.x;
            float g1 = (v[m*8+1]-mean)*rs*lw0.y + lb0.y;
            float g2 = (v[m*8+2]-mean)*rs*lw0.z + lb0.z;
            float g3 = (v[m*8+3]-mean)*rs*lw0.w + lb0.w;
            float g4 = (v[m*8+4]-mean)*rs*lw1.x + lb1.x;
            float g5 = (v[m*8+5]-mean)*rs*lw1.y + lb1.y;
            float g6 = (v[m*8+6]-mean)*rs*lw1.z + lb1.z;
            float g7 = (v[m*8+7]-mean)*rs*lw1.w + lb1.w;
            uint4 pk;
            pk.x = f2bf(g0) | ((uint)f2bf(g1) << 16);
            pk.y = f2bf(g2) | ((uint)f2bf(g3) << 16);
            pk.z = f2bf(g4) | ((uint)f2bf(g5) << 16);
            pk.w = f2bf(g6) | ((uint)f2bf(g7) << 16);
            xnf[m] = __builtin_bit_cast(bf16x8, pk);
        }

        // prefetch next batch into the just-freed v[] (overlaps both GEMMs)
        if (b + 1 < BPW) {
            const float* xq = x + (tb + BATCH + tk) * (size_t)DD;
#pragma unroll
            for (int m = 0; m < 4; ++m) {
                *(float4*)(v + m*8)     = *(const float4*)(xq + m*32 + cs*8);
                *(float4*)(v + m*8 + 4) = *(const float4*)(xq + m*32 + cs*8 + 4);
            }
        }

        // ---- GEMM1 (swapped): D1[j][tok], acc init = b1 ----
        f32x4 acc1[8];
#pragma unroll
        for (int jt = 0; jt < 8; ++jt) acc1[jt] = b1v[jt];
#pragma unroll
        for (int ks = 0; ks < 4; ++ks)
#pragma unroll
            for (int jt = 0; jt < 8; ++jt)
                acc1[jt] = __builtin_amdgcn_mfma_f32_16x16x32_bf16(
                    w1f[jt][ks], xnf[ks], acc1[jt], 0, 0, 0);

        // ---- gelu + per-wave LDS transpose (write h[tok][j], XOR-swizzled) --
#pragma unroll
        for (int jt = 0; jt < 8; ++jt) {
            float g0 = gelu_f(acc1[jt][0]);
            float g1 = gelu_f(acc1[jt][1]);
            float g2 = gelu_f(acc1[jt][2]);
            float g3 = gelu_f(acc1[jt][3]);
            uint2 pk2;
            pk2.x = f2bf(g0) | ((uint)f2bf(g1) << 16);
            pk2.y = f2bf(g2) | ((uint)f2bf(g3) << 16);
            int c16 = (jt*2 + (cs >> 1)) ^ tk;        // 16B-chunk swizzle
            *(uint2*)(hbase + tk*256 + c16*16 + (cs & 1)*8) = pk2;
        }
        bf16x8 B2[4];                      // read back as GEMM2 B-frags
#pragma unroll
        for (int ks = 0; ks < 4; ++ks) {
            int c16 = (ks*4 + cs) ^ tk;
            B2[ks] = *(const bf16x8*)(hbase + tk*256 + c16*16);
        }

        // ---- GEMM2 (swapped): D2[k][tok], acc init = -czero ----
        f32x4 acc2[4];
#pragma unroll
        for (int kt = 0; kt < 4; ++kt) acc2[kt] = czv[kt];
#pragma unroll
        for (int ks = 0; ks < 4; ++ks)
#pragma unroll
            for (int kt = 0; kt < 4; ++kt)
                acc2[kt] = __builtin_amdgcn_mfma_f32_16x16x32_bf16(
                    w2f[kt][ks], B2[ks], acc2[kt], 0, 0, 0);

        // ---- scatter into block accumulator (stride-65: conflict-light) ----
#pragma unroll
        for (int kt = 0; kt < 4; ++kt)
#pragma unroll
            for (int r = 0; r < 4; ++r)
                atomicAdd(&s_acc[lg*65 + kt*16 + cs*4 + r], acc2[kt][r]);
    }

    __syncthreads();                       // barrier 2: all waves done

    {   // flush block accumulator -> partial buffers
        int t8 = (bid >> 6) * LCOMP;       // 64 blocks per t
        int p  = bid & (NPART - 1);
        for (int idx = tid; idx < LCOMP * CDIM; idx += 256) {
            int l = idx >> 6, k = idx & 63;
            atomicAdd(&csum_p[(p * 64 + t8 + l) * 64 + k], s_acc[l*65 + k]);
        }
    }
}

// ---------------- finalize: reduce partials, comp, LN(512), ortho loss ------
__global__ void fin_kernel(const float* __restrict__ csum_p, const float* __restrict__ czero,
                           const float* __restrict__ b2,
                           const float* __restrict__ lnfw, const float* __restrict__ lnfb,
                           float* __restrict__ out) {
    __shared__ float comp[TT * LCOMP * CDIM];
    __shared__ float norm_s[LCOMP], sum_s[LCOMP], red[8];
    int tid = threadIdx.x;

    for (int idx = tid; idx < TT * LCOMP * CDIM; idx += 512) {
        int bin = idx >> 6, k = idx & 63;
        float s = 0.f;
        for (int p = 0; p < NPART; ++p) s += csum_p[(p * 64 + bin) * 64 + k];
        comp[idx] = s * (1.f / GSZ) + czero[k] + b2[k];
    }
    __syncthreads();

    int wave = tid >> 6, lane = tid & 63;

    {   // per-t LayerNorm over 512
        int t = wave;
        float s = 0.f, q = 0.f;
        for (int e = lane; e < 512; e += 64) {
            float v = comp[t * 512 + e];
            s += v; q += v * v;
        }
#pragma unroll
        for (int off = 32; off > 0; off >>= 1) {
            s += __shfl_xor(s, off, 64);
            q += __shfl_xor(q, off, 64);
        }
        float m = s * (1.f / 512.f);
        float var = q * (1.f / 512.f) - m * m;
        float rs = rsqrtf(var + 1e-5f);
        for (int e = lane; e < 512; e += 64) {
            float v = comp[t * 512 + e];
            out[t * 512 + e] = (v - m) * rs * lnfw[e] + lnfb[e];
        }
    }

    {   // per-l norm and sum of f[l]
        int l = wave;
        float s2 = 0.f, s1 = 0.f;
        for (int qd = lane; qd < 512; qd += 64) {
            int t = qd >> 6, k = qd & 63;
            float v = comp[t * 512 + l * 64 + k];
            s2 += v * v; s1 += v;
        }
#pragma unroll
        for (int off = 32; off > 0; off >>= 1) {
            s2 += __shfl_xor(s2, off, 64);
            s1 += __shfl_xor(s1, off, 64);
        }
        if (lane == 0) { norm_s[l] = sqrtf(s2); sum_s[l] = s1; }
    }
    __syncthreads();

    float loss_part = 0.f;
    for (int p = wave; p < 49; p += 8) {
        int i = p / 7, j = 1 + p % 7;
        float d = 0.f;
        for (int qd = lane; qd < 512; qd += 64) {
            int t = qd >> 6, k = qd & 63;
            d += comp[t * 512 + i * 64 + k] * comp[t * 512 + j * 64 + k];
        }
#pragma unroll
        for (int off = 32; off > 0; off >>= 1) d += __shfl_xor(d, off, 64);
        float ni = norm_s[i], nj = norm_s[j];
        float dot = (d / (ni * nj)) / (sum_s[i] / ni + sum_s[j] / nj);
        loss_part += dot * dot;
    }
    if (lane == 0) red[wave] = loss_part;
    __syncthreads();
    if (tid == 0) {
        float tot = 0.f;
        for (int w2_ = 0; w2_ < 8; ++w2_) tot += red[w2_];
        out[4096] = tot * (1.f / 49.f);
    }
}

extern "C" void kernel_launch(void* const* d_in, const int* in_sizes, int n_in,
                              void* d_out, int out_size, void* d_ws, size_t ws_size,
                              hipStream_t stream) {
    const float* x    = (const float*)d_in[0];
    const float* ln1w = (const float*)d_in[1];
    const float* ln1b = (const float*)d_in[2];
    const float* w1   = (const float*)d_in[3];
    const float* b1   = (const float*)d_in[4];
    const float* w2   = (const float*)d_in[5];
    const float* b2   = (const float*)d_in[6];
    const float* lnfw = (const float*)d_in[7];
    const float* lnfb = (const float*)d_in[8];
    const int* node_idx = (const int*)d_in[10];
    float* out = (float*)d_out;

    char* wsb = (char*)d_ws;
    float*  czero  = (float*)(wsb + O_CZERO);
    ushort* w2bt   = (ushort*)(wsb + O_W2BT);
    ushort* w1bt   = (ushort*)(wsb + O_W1BT);
    float*  csum_p = (float*)(wsb + O_CSUMP);

    prep_kernel<<<64, 256, 0, stream>>>(w1, b1, w2, w1bt, w2bt, czero, csum_p);
    main_kernel<<<NBLK, 256, 0, stream>>>(x, ln1w, ln1b, b1, w1bt, w2bt, czero,
                                          node_idx, csum_p);
    fin_kernel<<<1, 512, 0, stream>>>(csum_p, czero, b2, lnfw, lnfb, out);
}

// Round 12
// 380.240 us; speedup vs baseline: 1.0282x; 1.0282x over previous
//
#include <hip/hip_runtime.h>
#include <math.h>

// Problem constants
#define TT 8
#define NTOK 32768
#define DD 128
#define LCOMP 8
#define GSZ 8192
#define CDIM 64
#define EDIM 128
#define NPART 8

#define BATCH 16                       // tokens per wave-batch
#define BPW 8                          // batches per wave
#define WAVES 4
#define TOKBLK (WAVES*BPW*BATCH)       // 512 tokens per block
#define NBLK (TT*NTOK/TOKBLK)          // 512 blocks = 2/CU, all resident

// workspace byte offsets
#define O_CZERO 0                            // 64 f32
#define O_W2BT  256                          // 64*128 bf16 [k][j] linear
#define O_W1BT  (256 + EDIM*CDIM*2)          // 128*128 bf16 [j][d] linear
#define O_CSUMP (O_W1BT + DD*EDIM*2)         // 8*64*64 f32 partials

typedef __attribute__((ext_vector_type(8))) short bf16x8;
typedef __attribute__((ext_vector_type(4))) float f32x4;

__device__ __forceinline__ ushort f2bf(float f) {
    union { float f; uint u; } c; c.f = f;
    uint u = c.u;
    return (ushort)((u + 0x7FFFu + ((u >> 16) & 1u)) >> 16);
}

// gelu via Abramowitz-Stegun 7.1.26 erf (|eps| <= 1.5e-7)
__device__ __forceinline__ float gelu_f(float a) {
    float x = a * 0.70710678118654752f;
    float ax = fabsf(x);
    float t = 1.0f / (1.0f + 0.3275911f * ax);
    float p = t * (0.254829592f + t * (-0.284496736f + t * (1.421413741f +
              t * (-1.453152027f + t * 1.061405429f))));
    float e = __expf(-x * x);
    float er = copysignf(1.0f - p * e, x);
    return 0.5f * a * (1.0f + er);
}

// ---------------- prep: bf16 transposed weights (linear), czero, zero csum_p
__global__ void prep_kernel(const float* __restrict__ w1, const float* __restrict__ b1,
                            const float* __restrict__ w2,
                            ushort* __restrict__ w1bt, ushort* __restrict__ w2bt,
                            float* __restrict__ czero, float* __restrict__ csum_p) {
    int gid = blockIdx.x * 256 + threadIdx.x;
    if (gid < DD * EDIM) {                 // w1bt[j][d] linear (register A-frags)
        int j = gid >> 7, d = gid & 127;
        w1bt[j * 128 + d] = f2bf(w1[d * EDIM + j]);
    }
    if (gid < EDIM * CDIM) {               // w2bt[k][j] linear
        int k = gid >> 7, jj = gid & 127;
        w2bt[k * 128 + jj] = f2bf(w2[jj * CDIM + k]);
    }
    if (gid < CDIM) {
        float a2 = 0.f;
        for (int dd = 0; dd < EDIM; ++dd)
            a2 += gelu_f(b1[dd]) * w2[dd * CDIM + gid];
        czero[gid] = a2;
    }
#pragma unroll
    for (int i = 0; i < 2; ++i)            // zero 8*64*64 partial sums
        csum_p[gid + i * 16384] = 0.f;
}

// ---------------- main: barrier-free per-wave LN+MLP, swapped-operand MFMA --
// Swapped GEMMs: D1[j][tok]=w1t·xn, D2[k][tok]=w2t·h. B-frag (col=tok,
// k=(l>>4)*8+e) == the strided x load, so xn feeds MFMA from registers.
// Weights in registers; h transposed through a 4KB PER-WAVE LDS patch
// (same-wave ds ops, lgkmcnt-ordered, NO __syncthreads in the loop).
// R11 lesson: v[] loads MUST be elementwise — *(float4*)(v+..) address-takes
// the array -> scratch (262MB excess FETCH, 83MB WRITE measured).
__global__ __launch_bounds__(256, 2)
void main_kernel(const float* __restrict__ x,
                 const float* __restrict__ ln1w, const float* __restrict__ ln1b,
                 const float* __restrict__ b1g,
                 const ushort* __restrict__ w1bt, const ushort* __restrict__ w2bt,
                 const float* __restrict__ czero,
                 const int* __restrict__ node_idx,
                 float* __restrict__ csum_p) {
    __shared__ ushort s_h[WAVES * 2048];   // 4KB per wave: h[16tok][128j] bf16 swizzled
    __shared__ float  s_acc[LCOMP * 65];   // stride-65 pad

    const int tid = threadIdx.x;
    const int w   = tid >> 6;
    const int ln  = tid & 63;
    const int cs  = ln >> 4;               // k-slice group (4 lanes per token)
    const int tk  = ln & 15;               // token-in-batch = MFMA col
    const int bid = blockIdx.x;

    for (int idx = tid; idx < LCOMP * 65; idx += 256) s_acc[idx] = 0.f;

    // ---- persistent register state (whole wave lifetime) ----
    bf16x8 w1f[8][4];                      // A-frags of w1t: 64 VGPR
#pragma unroll
    for (int jt = 0; jt < 8; ++jt)
#pragma unroll
        for (int ks = 0; ks < 4; ++ks)
            w1f[jt][ks] = *(const bf16x8*)(w1bt + (jt*16 + tk)*128 + ks*32 + cs*8);
    bf16x8 w2f[4][4];                      // A-frags of w2t: 32 VGPR
#pragma unroll
    for (int kt = 0; kt < 4; ++kt)
#pragma unroll
        for (int ks = 0; ks < 4; ++ks)
            w2f[kt][ks] = *(const bf16x8*)(w2bt + (kt*16 + tk)*128 + ks*32 + cs*8);

    __syncthreads();                       // barrier 1: s_acc zeroed

    const size_t wbase = (size_t)bid * TOKBLK + w * (BPW * BATCH);
    char* hbase = (char*)s_h + w * 4096;

    // preload batch 0: lane holds x[tok=tk][d in {m*32+cs*8 .. +8}] (B-frag layout)
    float v[32];
    {
        const float* xp = x + (wbase + tk) * (size_t)DD + cs * 8;
#pragma unroll
        for (int m = 0; m < 4; ++m) {
            float4 a = *(const float4*)(xp + m*32);
            float4 b = *(const float4*)(xp + m*32 + 4);
            v[m*8+0]=a.x; v[m*8+1]=a.y; v[m*8+2]=a.z; v[m*8+3]=a.w;
            v[m*8+4]=b.x; v[m*8+5]=b.y; v[m*8+6]=b.z; v[m*8+7]=b.w;
        }
    }

    for (int b = 0; b < BPW; ++b) {
        const size_t tb = wbase + (size_t)b * BATCH;
        const int lg = node_idx[tb + tk] >> 13;   // token's group

        // ---- LayerNorm (4 lanes/token via xor 16,32) ----
        float s = 0.f, q = 0.f;
#pragma unroll
        for (int i = 0; i < 32; ++i) { s += v[i]; q += v[i]*v[i]; }
        s += __shfl_xor(s, 16, 64); q += __shfl_xor(q, 16, 64);
        s += __shfl_xor(s, 32, 64); q += __shfl_xor(q, 32, 64);
        float mean = s * (1.f/128.f);
        float var  = q * (1.f/128.f) - mean*mean;
        float rs   = rsqrtf(var + 1e-5f);

        bf16x8 xnf[4];                     // = GEMM1 B-frags, built in-register
#pragma unroll
        for (int m = 0; m < 4; ++m) {
            const float* lwp = ln1w + m*32 + cs*8;
            const float* lbp = ln1b + m*32 + cs*8;
            float4 lw0 = *(const float4*)(lwp),   lw1 = *(const float4*)(lwp + 4);
            float4 lb0 = *(const float4*)(lbp),   lb1 = *(const float4*)(lbp + 4);
            float g0 = (v[m*8+0]-mean)*rs*lw0.x + lb0.x;
            float g1 = (v[m*8+1]-mean)*rs*lw0.y + lb0.y;
            float g2 = (v[m*8+2]-mean)*rs*lw0.z + lb0.z;
            float g3 = (v[m*8+3]-mean)*rs*lw0.w + lb0.w;
            float g4 = (v[m*8+4]-mean)*rs*lw1.x + lb1.x;
            float g5 = (v[m*8+5]-mean)*rs*lw1.y + lb1.y;
            float g6 = (v[m*8+6]-mean)*rs*lw1.z + lb1.z;
            float g7 = (v[m*8+7]-mean)*rs*lw1.w + lb1.w;
            uint4 pk;
            pk.x = f2bf(g0) | ((uint)f2bf(g1) << 16);
            pk.y = f2bf(g2) | ((uint)f2bf(g3) << 16);
            pk.z = f2bf(g4) | ((uint)f2bf(g5) << 16);
            pk.w = f2bf(g6) | ((uint)f2bf(g7) << 16);
            xnf[m] = __builtin_bit_cast(bf16x8, pk);
        }

        // prefetch next batch into the just-freed v[] (elementwise! registers)
        if (b + 1 < BPW) {
            const float* xq = x + (tb + BATCH + tk) * (size_t)DD + cs * 8;
#pragma unroll
            for (int m = 0; m < 4; ++m) {
                float4 a = *(const float4*)(xq + m*32);
                float4 bb = *(const float4*)(xq + m*32 + 4);
                v[m*8+0]=a.x;  v[m*8+1]=a.y;  v[m*8+2]=a.z;  v[m*8+3]=a.w;
                v[m*8+4]=bb.x; v[m*8+5]=bb.y; v[m*8+6]=bb.z; v[m*8+7]=bb.w;
            }
        }

        // ---- GEMM1 (swapped): D1[j][tok], acc = 0, bias added at gelu ----
        f32x4 acc1[8];
#pragma unroll
        for (int jt = 0; jt < 8; ++jt) acc1[jt] = (f32x4){0.f,0.f,0.f,0.f};
#pragma unroll
        for (int ks = 0; ks < 4; ++ks)
#pragma unroll
            for (int jt = 0; jt < 8; ++jt)
                acc1[jt] = __builtin_amdgcn_mfma_f32_16x16x32_bf16(
                    w1f[jt][ks], xnf[ks], acc1[jt], 0, 0, 0);

        // ---- gelu(+b1) + per-wave LDS transpose (h[tok][j], XOR-swizzled) --
#pragma unroll
        for (int jt = 0; jt < 8; ++jt) {
            float g0 = gelu_f(acc1[jt][0] + b1g[jt*16 + cs*4 + 0]);
            float g1 = gelu_f(acc1[jt][1] + b1g[jt*16 + cs*4 + 1]);
            float g2 = gelu_f(acc1[jt][2] + b1g[jt*16 + cs*4 + 2]);
            float g3 = gelu_f(acc1[jt][3] + b1g[jt*16 + cs*4 + 3]);
            uint2 pk2;
            pk2.x = f2bf(g0) | ((uint)f2bf(g1) << 16);
            pk2.y = f2bf(g2) | ((uint)f2bf(g3) << 16);
            int c16 = (jt*2 + (cs >> 1)) ^ tk;        // 16B-chunk swizzle
            *(uint2*)(hbase + tk*256 + c16*16 + (cs & 1)*8) = pk2;
        }
        bf16x8 B2[4];                      // read back as GEMM2 B-frags
#pragma unroll
        for (int ks = 0; ks < 4; ++ks) {
            int c16 = (ks*4 + cs) ^ tk;
            B2[ks] = *(const bf16x8*)(hbase + tk*256 + c16*16);
        }

        // ---- GEMM2 (swapped): D2[k][tok], acc = 0, czero subtracted below --
        f32x4 acc2[4];
#pragma unroll
        for (int kt = 0; kt < 4; ++kt) acc2[kt] = (f32x4){0.f,0.f,0.f,0.f};
#pragma unroll
        for (int ks = 0; ks < 4; ++ks)
#pragma unroll
            for (int kt = 0; kt < 4; ++kt)
                acc2[kt] = __builtin_amdgcn_mfma_f32_16x16x32_bf16(
                    w2f[kt][ks], B2[ks], acc2[kt], 0, 0, 0);

        // ---- scatter into block accumulator ----
#pragma unroll
        for (int kt = 0; kt < 4; ++kt)
#pragma unroll
            for (int r = 0; r < 4; ++r)
                atomicAdd(&s_acc[lg*65 + kt*16 + cs*4 + r],
                          acc2[kt][r] - czero[kt*16 + cs*4 + r]);
    }

    __syncthreads();                       // barrier 2: all waves done

    {   // flush block accumulator -> partial buffers
        int t8 = (bid >> 6) * LCOMP;       // 64 blocks per t
        int p  = bid & (NPART - 1);
        for (int idx = tid; idx < LCOMP * CDIM; idx += 256) {
            int l = idx >> 6, k = idx & 63;
            atomicAdd(&csum_p[(p * 64 + t8 + l) * 64 + k], s_acc[l*65 + k]);
        }
    }
}

// ---------------- finalize: reduce partials, comp, LN(512), ortho loss ------
__global__ void fin_kernel(const float* __restrict__ csum_p, const float* __restrict__ czero,
                           const float* __restrict__ b2,
                           const float* __restrict__ lnfw, const float* __restrict__ lnfb,
                           float* __restrict__ out) {
    __shared__ float comp[TT * LCOMP * CDIM];
    __shared__ float norm_s[LCOMP], sum_s[LCOMP], red[8];
    int tid = threadIdx.x;

    for (int idx = tid; idx < TT * LCOMP * CDIM; idx += 512) {
        int bin = idx >> 6, k = idx & 63;
        float s = 0.f;
        for (int p = 0; p < NPART; ++p) s += csum_p[(p * 64 + bin) * 64 + k];
        comp[idx] = s * (1.f / GSZ) + czero[k] + b2[k];
    }
    __syncthreads();

    int wave = tid >> 6, lane = tid & 63;

    {   // per-t LayerNorm over 512
        int t = wave;
        float s = 0.f, q = 0.f;
        for (int e = lane; e < 512; e += 64) {
            float v = comp[t * 512 + e];
            s += v; q += v * v;
        }
#pragma unroll
        for (int off = 32; off > 0; off >>= 1) {
            s += __shfl_xor(s, off, 64);
            q += __shfl_xor(q, off, 64);
        }
        float m = s * (1.f / 512.f);
        float var = q * (1.f / 512.f) - m * m;
        float rs = rsqrtf(var + 1e-5f);
        for (int e = lane; e < 512; e += 64) {
            float v = comp[t * 512 + e];
            out[t * 512 + e] = (v - m) * rs * lnfw[e] + lnfb[e];
        }
    }

    {   // per-l norm and sum of f[l]
        int l = wave;
        float s2 = 0.f, s1 = 0.f;
        for (int qd = lane; qd < 512; qd += 64) {
            int t = qd >> 6, k = qd & 63;
            float v = comp[t * 512 + l * 64 + k];
            s2 += v * v; s1 += v;
        }
#pragma unroll
        for (int off = 32; off > 0; off >>= 1) {
            s2 += __shfl_xor(s2, off, 64);
            s1 += __shfl_xor(s1, off, 64);
        }
        if (lane == 0) { norm_s[l] = sqrtf(s2); sum_s[l] = s1; }
    }
    __syncthreads();

    float loss_part = 0.f;
    for (int p = wave; p < 49; p += 8) {
        int i = p / 7, j = 1 + p % 7;
        float d = 0.f;
        for (int qd = lane; qd < 512; qd += 64) {
            int t = qd >> 6, k = qd & 63;
            d += comp[t * 512 + i * 64 + k] * comp[t * 512 + j * 64 + k];
        }
#pragma unroll
        for (int off = 32; off > 0; off >>= 1) d += __shfl_xor(d, off, 64);
        float ni = norm_s[i], nj = norm_s[j];
        float dot = (d / (ni * nj)) / (sum_s[i] / ni + sum_s[j] / nj);
        loss_part += dot * dot;
    }
    if (lane == 0) red[wave] = loss_part;
    __syncthreads();
    if (tid == 0) {
        float tot = 0.f;
        for (int w2_ = 0; w2_ < 8; ++w2_) tot += red[w2_];
        out[4096] = tot * (1.f / 49.f);
    }
}

extern "C" void kernel_launch(void* const* d_in, const int* in_sizes, int n_in,
                              void* d_out, int out_size, void* d_ws, size_t ws_size,
                              hipStream_t stream) {
    const float* x    = (const float*)d_in[0];
    const float* ln1w = (const float*)d_in[1];
    const float* ln1b = (const float*)d_in[2];
    const float* w1   = (const float*)d_in[3];
    const float* b1   = (const float*)d_in[4];
    const float* w2   = (const float*)d_in[5];
    const float* b2   = (const float*)d_in[6];
    const float* lnfw = (const float*)d_in[7];
    const float* lnfb = (const float*)d_in[8];
    const int* node_idx = (const int*)d_in[10];
    float* out = (float*)d_out;

    char* wsb = (char*)d_ws;
    float*  czero  = (float*)(wsb + O_CZERO);
    ushort* w2bt   = (ushort*)(wsb + O_W2BT);
    ushort* w1bt   = (ushort*)(wsb + O_W1BT);
    float*  csum_p = (float*)(wsb + O_CSUMP);

    prep_kernel<<<64, 256, 0, stream>>>(w1, b1, w2, w1bt, w2bt, czero, csum_p);
    main_kernel<<<NBLK, 256, 0, stream>>>(x, ln1w, ln1b, b1, w1bt, w2bt, czero,
                                          node_idx, csum_p);
    fin_kernel<<<1, 512, 0, stream>>>(csum_p, czero, b2, lnfw, lnfb, out);
}